// Round 11
// baseline (537.553 us; speedup 1.0000x reference)
//
#include <hip/hip_runtime.h>

typedef unsigned short u16;
typedef unsigned int u32;
typedef __attribute__((ext_vector_type(8))) short s8v;
typedef __attribute__((ext_vector_type(4))) float f4v;
typedef __attribute__((ext_vector_type(2))) float f2v;

#define NATOMS 200000
#define NBONDS 400000

// ---------- bf16 helpers ----------
__device__ __forceinline__ float b2f(u32 u) {
    union { u32 i; float f; } v; v.i = u << 16; return v.f;
}
__device__ __forceinline__ u16 f2b(float f) {
    union { float f; u32 i; } v; v.f = f;
    u32 r = v.i + 0x7fffu + ((v.i >> 16) & 1u);
    return (u16)(r >> 16);
}
__device__ __forceinline__ uint4 pack8(const float* f) {
    uint4 o;
    o.x = (u32)f2b(f[0]) | ((u32)f2b(f[1]) << 16);
    o.y = (u32)f2b(f[2]) | ((u32)f2b(f[3]) << 16);
    o.z = (u32)f2b(f[4]) | ((u32)f2b(f[5]) << 16);
    o.w = (u32)f2b(f[6]) | ((u32)f2b(f[7]) << 16);
    return o;
}
__device__ __forceinline__ void acc8(uint4 u, float* a) {
    a[0] += b2f(u.x & 0xffffu); a[1] += b2f(u.x >> 16);
    a[2] += b2f(u.y & 0xffffu); a[3] += b2f(u.y >> 16);
    a[4] += b2f(u.z & 0xffffu); a[5] += b2f(u.z >> 16);
    a[6] += b2f(u.w & 0xffffu); a[7] += b2f(u.w >> 16);
}

// ---------- cross-lane (DPP xor1/xor2 + DS xor4 + DPP ror8) ----------
template<int C>
__device__ __forceinline__ float dpp_mov_f(float x) {
    return __int_as_float(__builtin_amdgcn_update_dpp(
        0, __float_as_int(x), C, 0xF, 0xF, true));
}
__device__ __forceinline__ float swz_xor4(float x) {
    return __int_as_float(__builtin_amdgcn_ds_swizzle(__float_as_int(x), 0x101F));
}
__device__ __forceinline__ float red16(float x) {  // sum over lane bits 0..3
    x += dpp_mov_f<0xB1>(x);
    x += dpp_mov_f<0x4E>(x);
    x += swz_xor4(x);
    x += dpp_mov_f<0x128>(x);
    return x;
}
// reduce-scatter over 8 lanes: lane with (l3 == j) returns sum_l x[j](l).
// 3 phases of recursive halving (xor1, xor2, xor4); ~28 ops vs 48 for 8 butterflies.
__device__ __forceinline__ float rscat8(const float* x, int l3) {
    const bool b0 = (l3 & 1), b1 = (l3 & 2), b2 = (l3 & 4);
    float y0 = (b0 ? x[1] : x[0]) + dpp_mov_f<0xB1>(b0 ? x[0] : x[1]);
    float y1 = (b0 ? x[3] : x[2]) + dpp_mov_f<0xB1>(b0 ? x[2] : x[3]);
    float y2 = (b0 ? x[5] : x[4]) + dpp_mov_f<0xB1>(b0 ? x[4] : x[5]);
    float y3 = (b0 ? x[7] : x[6]) + dpp_mov_f<0xB1>(b0 ? x[6] : x[7]);
    float z0 = (b1 ? y1 : y0) + dpp_mov_f<0x4E>(b1 ? y0 : y1);
    float z1 = (b1 ? y3 : y2) + dpp_mov_f<0x4E>(b1 ? y2 : y3);
    return (b2 ? z1 : z0) + swz_xor4(b2 ? z0 : z1);
}

// ---------- merged prep: weight repack + f_bonds bf16 table ----------
__global__ void k_prep(const float* __restrict__ Whq, const float* __restrict__ Whk,
                       const float* __restrict__ Whv, const float* __restrict__ Wo,
                       const float* __restrict__ Wi,
                       u16* __restrict__ wallw, u16* __restrict__ wow, u16* __restrict__ wiw,
                       const float* __restrict__ fb, u16* __restrict__ fbw) {
    if (blockIdx.x < 1168) {
        int t = blockIdx.x * 256 + threadIdx.x;
        if (t < 245760) {
            int ks = t / 24576, rem = t % 24576;
            int n = rem >> 5, kk = rem & 31;
            int k = ks * 32 + kk;
            int hg = n / 48, r48 = n % 48;
            int branch = r48 >> 4, r16i = r48 & 15;
            int head = r16i >> 3, h = hg * 8 + (r16i & 7);
            const float* Wp = (branch == 0) ? Whq : ((branch == 1) ? Whk : Whv);
            float val = (k < 293) ? Wp[(head * 293 + k) * 128 + h] : 0.f;
            wallw[t] = f2b(val);
        } else if (t < 278528) {
            int u = t - 245760;
            int ks = u >> 12, n = (u >> 5) & 127, kk = u & 31;
            int k = ks * 32 + kk;
            wow[u] = f2b(Wo[k * 128 + n]);
        } else if (t < 299008) {
            int u = t - 278528;
            int ks = u >> 12, n = (u >> 5) & 127, kk = u & 31;
            int k = ks * 32 + kk;
            wiw[u] = (k < 151) ? f2b(Wi[k * 128 + n]) : (u16)0;
        }
    } else {
        int t = (blockIdx.x - 1168) * 256 + threadIdx.x;
        if (t >= NBONDS * 21) return;
        u32 b = (u32)t / 21u, c = (u32)t % 21u;
        const float* src = fb + (size_t)b * 165 + c * 8;
        float a[8];
        #pragma unroll
        for (int q = 0; q < 8; q++) a[q] = ((int)(c * 8 + q) < 165) ? src[q] : 0.f;
        *(uint4*)&fbw[(size_t)b * 168 + c * 8] = pack8(a);
    }
}

// ---------- merged per-atom gather-sums ----------
__global__ void k_msgab(const u16* __restrict__ h0w, const int* __restrict__ a2a,
                        u16* __restrict__ msga,
                        const u16* __restrict__ fbw, const int* __restrict__ a2b,
                        u16* __restrict__ msgb) {
    if (blockIdx.x < 12500) {
        int t = blockIdx.x * 256 + threadIdx.x;
        if (t >= NATOMS * 16) return;
        u32 atom = (u32)t >> 4, c = (u32)t & 15u;
        const int* na = a2a + (size_t)atom * 6;
        float a[8] = {0, 0, 0, 0, 0, 0, 0, 0};
        #pragma unroll
        for (int j = 0; j < 6; j++)
            acc8(*(const uint4*)&h0w[(size_t)(u32)na[j] * 128 + c * 8], a);
        *(uint4*)&msga[(size_t)atom * 128 + c * 8] = pack8(a);
    } else {
        int t = (blockIdx.x - 12500) * 256 + threadIdx.x;
        if (t >= NATOMS * 21) return;
        u32 atom = (u32)t / 21u, c = (u32)t % 21u;
        const int* nb = a2b + (size_t)atom * 6;
        float a[8] = {0, 0, 0, 0, 0, 0, 0, 0};
        #pragma unroll
        for (int j = 0; j < 6; j++)
            acc8(*(const uint4*)&fbw[(size_t)(u32)nb[j] * 168 + c * 8], a);
        *(uint4*)&msgb[(size_t)atom * 168 + c * 8] = pack8(a);
    }
}

// ---------- h0 = LN(relu(f_atoms @ W_i + b_i)) -> bf16 (in-register LN) ----------
#define H0_SMEM 23552
__global__ __launch_bounds__(256) void k_h0(
    const float* __restrict__ fa, const u16* __restrict__ wiw,
    const float* __restrict__ bi, const float* __restrict__ g1p, const float* __restrict__ b1p,
    u16* __restrict__ h0w) {
    extern __shared__ char smem[];
    u16* la = (u16*)smem;                 // [64][168]
    float* pp = (float*)(smem + 21504);   // [64][4][2]
    const int tid = threadIdx.x;
    const size_t abase = (size_t)blockIdx.x * 64;

    for (int i = tid; i < 64 * 151; i += 256) {
        int r = i / 151, c = i - r * 151;
        la[r * 168 + c] = f2b(fa[(abase + r) * 151 + c]);
    }
    for (int i = tid; i < 64 * 17; i += 256) {
        int r = i / 17, c = i - r * 17;
        la[r * 168 + 151 + c] = 0;
    }
    __syncthreads();

    const int w = tid >> 6, l = tid & 63;
    const int r16 = l & 15, kq = l >> 4;
    f4v acc[4][2];
    #pragma unroll
    for (int m = 0; m < 4; m++)
        #pragma unroll
        for (int c = 0; c < 2; c++)
            #pragma unroll
            for (int v = 0; v < 4; v++) acc[m][c][v] = 0.f;

    #pragma unroll
    for (int ks = 0; ks < 5; ++ks) {
        s8v af[4];
        #pragma unroll
        for (int m = 0; m < 4; m++)
            af[m] = *(const s8v*)&la[(m * 16 + r16) * 168 + ks * 32 + kq * 8];
        #pragma unroll
        for (int c = 0; c < 2; c++) {
            int n = w * 32 + c * 16 + r16;
            s8v bf = *(const s8v*)&wiw[ks * 4096 + n * 32 + kq * 8];
            #pragma unroll
            for (int m = 0; m < 4; m++)
                acc[m][c] = __builtin_amdgcn_mfma_f32_16x16x32_bf16(af[m], bf, acc[m][c], 0, 0, 0);
        }
    }

    const int col0 = w * 32 + r16, col1 = col0 + 16;
    const float bi0 = bi[col0], bi1 = bi[col1];
    #pragma unroll
    for (int m = 0; m < 4; m++) {
        #pragma unroll
        for (int v = 0; v < 4; v++) {
            acc[m][0][v] = fmaxf(acc[m][0][v] + bi0, 0.f);
            acc[m][1][v] = fmaxf(acc[m][1][v] + bi1, 0.f);
            float s = red16(acc[m][0][v] + acc[m][1][v]);
            float s2 = red16(acc[m][0][v] * acc[m][0][v] + acc[m][1][v] * acc[m][1][v]);
            if (r16 == 0) {
                int row = m * 16 + kq * 4 + v;
                f2v pr; pr[0] = s; pr[1] = s2;
                *(f2v*)&pp[(row * 4 + w) * 2] = pr;
            }
        }
    }
    __syncthreads();

    const float g0 = g1p[col0], g1v = g1p[col1];
    const float e0 = b1p[col0], e1 = b1p[col1];
    #pragma unroll
    for (int m = 0; m < 4; m++) {
        #pragma unroll
        for (int v = 0; v < 4; v++) {
            int row = m * 16 + kq * 4 + v;
            f4v p0 = *(f4v*)&pp[row * 8];
            f4v p1 = *(f4v*)&pp[row * 8 + 4];
            float ssum = p0[0] + p0[2] + p1[0] + p1[2];
            float s2sum = p0[1] + p0[3] + p1[1] + p1[3];
            float mu = ssum * (1.f / 128.f);
            float var = s2sum * (1.f / 128.f) - mu * mu;
            float rs = rsqrtf(var + 1e-5f);
            u16* orow = h0w + (abase + row) * 128;
            orow[col0] = f2b(g0 * (acc[m][0][v] - mu) * rs + e0);
            orow[col1] = f2b(g1v * (acc[m][1][v] - mu) * rs + e1);
        }
    }
}

// ---------- fused: coalesced stage + QKV proj + attention + W_o + LN2 + residual ----------
// 32 atoms/block, 1024 threads (16 waves), 2 blocks/CU (LDS 29184, VGPR<=64).
// LDS region0 @0 (20480): lmsg [32][320] bf16 XOR-swizzled (K-loop)
//   after B1.5 overlays: sco2 f32 [16][32][4] @0 (8192)
//   after B3   overlays: lx bf16 [32][264] @0 (16896)
//   attn f32 [32][4] @16896 (512) | pp f32 [32][8][2] @17408 (2048)
// lh0 [32][136] bf16 @20480 (8704, whole kernel)
#define SMEM_FUSED 29184
__global__ __launch_bounds__(1024, 8) void k_fused(
    const u16* __restrict__ h0w, const u16* __restrict__ msga, const u16* __restrict__ msgb,
    const u16* __restrict__ wallw, const u16* __restrict__ wow,
    const float* __restrict__ bhq, const float* __restrict__ bhk, const float* __restrict__ bhv,
    const float* __restrict__ bo, const float* __restrict__ g2, const float* __restrict__ b2,
    float* __restrict__ out) {
    extern __shared__ char smem[];
    float* sco2 = (float*)smem;             // overlays lmsg after B1.5
    u16* lx = (u16*)smem;                   // overlays sco2 after B3
    float* attn = (float*)(smem + 16896);
    float* pp = (float*)(smem + 17408);
    u16* lh0 = (u16*)(smem + 20480);        // stride 136 (bank-spread)

    const int tid = threadIdx.x;
    const size_t abase = (size_t)blockIdx.x * 32;
    const int w = tid >> 6, l = tid & 63;
    const int r16 = l & 15, kq = l >> 4;
    const u32 xmask = (u32)((r16 & 7) << 4);

    // B-frag prefetch for first K-step (L2-resident wallw)
    const u16* bp = wallw + (size_t)(w * 48 + r16) * 32 + kq * 8;
    s8v bfA0 = *(const s8v*)&bp[0];
    s8v bfA1 = *(const s8v*)&bp[512];
    s8v bfA2 = *(const s8v*)&bp[1024];

    // stage own h0 tile (coalesced), stride 136
    if (tid < 512) {
        int r = tid >> 4, c8 = tid & 15;
        *(uint4*)&lh0[r * 136 + c8 * 8] = *(const uint4*)&h0w[(abase + r) * 128 + c8 * 8];
    }

    // stage msg tile into swizzled LDS — fully coalesced reads:
    // item c: 0..15 -> msga cols c*8 | 16..36 -> msgb cols (c-16)*8 | 37..39 -> zeros
    #pragma unroll
    for (int ii = 0; ii < 2; ++ii) {
        int i = tid + ii * 1024;
        if (i < 1280) {
            int r = i / 40, c = i - r * 40;
            uint4 val;
            if (c < 16) {
                val = *(const uint4*)&msga[(abase + r) * 128 + c * 8];
            } else if (c < 37) {
                val = *(const uint4*)&msgb[(abase + r) * 168 + (c - 16) * 8];
            } else {
                val = (uint4){0, 0, 0, 0};
            }
            *(uint4*)(smem + (((u32)(r * 640 + c * 16)) ^ ((u32)((r & 7) << 4)))) = val;
        }
    }
    __syncthreads();  // B1: lmsg + lh0 ready

    f4v acc[2][3];
    #pragma unroll
    for (int m = 0; m < 2; m++)
        #pragma unroll
        for (int c = 0; c < 3; c++)
            #pragma unroll
            for (int v = 0; v < 4; v++) acc[m][c][v] = 0.f;

    s8v bfB0, bfB1, bfB2;
    // K-loop: 10 steps, A from swizzled LDS, B double-buffered from L2, no barriers.
    #pragma unroll
    for (int kp = 0; kp < 5; ++kp) {
        {   // even step uses bfA, prefetch bfB
            const int ks = 2 * kp;
            const u16* nb = bp + (size_t)(ks + 1) * 24576;
            bfB0 = *(const s8v*)&nb[0];
            bfB1 = *(const s8v*)&nb[512];
            bfB2 = *(const s8v*)&nb[1024];
            #pragma unroll
            for (int m = 0; m < 2; m++) {
                s8v af = *(const s8v*)(smem +
                    (((u32)((m * 16 + r16) * 640 + ks * 64 + kq * 16)) ^ xmask));
                acc[m][0] = __builtin_amdgcn_mfma_f32_16x16x32_bf16(af, bfA0, acc[m][0], 0, 0, 0);
                acc[m][1] = __builtin_amdgcn_mfma_f32_16x16x32_bf16(af, bfA1, acc[m][1], 0, 0, 0);
                acc[m][2] = __builtin_amdgcn_mfma_f32_16x16x32_bf16(af, bfA2, acc[m][2], 0, 0, 0);
            }
        }
        {   // odd step uses bfB, prefetch bfA
            const int ks = 2 * kp + 1;
            if (kp < 4) {
                const u16* nb = bp + (size_t)(ks + 1) * 24576;
                bfA0 = *(const s8v*)&nb[0];
                bfA1 = *(const s8v*)&nb[512];
                bfA2 = *(const s8v*)&nb[1024];
            }
            #pragma unroll
            for (int m = 0; m < 2; m++) {
                s8v af = *(const s8v*)(smem +
                    (((u32)((m * 16 + r16) * 640 + ks * 64 + kq * 16)) ^ xmask));
                acc[m][0] = __builtin_amdgcn_mfma_f32_16x16x32_bf16(af, bfB0, acc[m][0], 0, 0, 0);
                acc[m][1] = __builtin_amdgcn_mfma_f32_16x16x32_bf16(af, bfB1, acc[m][1], 0, 0, 0);
                acc[m][2] = __builtin_amdgcn_mfma_f32_16x16x32_bf16(af, bfB2, acc[m][2], 0, 0, 0);
            }
        }
    }
    __syncthreads();  // B1.5: lmsg reads done -> region0 reusable as sco2

    // QKV relu; QK score partials via reduce-scatter (lane j=r16&7 owns sum j).
    const int head = r16 >> 3;
    const int h = w * 8 + (r16 & 7);
    const float bq = bhq[head * 128 + h];
    const float bk = bhk[head * 128 + h];
    const float bv = bhv[head * 128 + h];
    float xA[8], xB[8];
    #pragma unroll
    for (int m = 0; m < 2; m++) {
        #pragma unroll
        for (int v = 0; v < 4; v++) {
            int row = m * 16 + kq * 4 + v;
            float h0v = b2f(lh0[row * 136 + h]);
            float q  = fmaxf(acc[m][0][v] + h0v + bq, 0.f);
            float kk = fmaxf(acc[m][1][v] + h0v + bk, 0.f);
            float vv = fmaxf(acc[m][2][v] + h0v + bv, 0.f);
            acc[m][2][v] = vv;  // keep relu'd V
            xA[m * 4 + v] = q * kk;                         // own-head partial
            xB[m * 4 + v] = q * dpp_mov_f<0x128>(kk);       // cross-head partial
        }
    }
    {
        const int j = r16 & 7;
        float pA = rscat8(xA, j);
        float pB = rscat8(xB, j);
        int row = (j >> 2) * 16 + kq * 4 + (j & 3);
        f2v pr; pr[0] = pA; pr[1] = pB;
        *(f2v*)&sco2[(w * 32 + row) * 4 + head * 2] = pr;
    }
    __syncthreads();  // B2: sco2 ready

    // softmax over heads: 64 threads, one per (atom, query-head)
    if (tid < 64) {
        int atom = tid >> 1, qh = tid & 1;
        float ss = 0.f, sx = 0.f;
        #pragma unroll
        for (int ww = 0; ww < 16; ww++) {
            f2v p = *(const f2v*)&sco2[(ww * 32 + atom) * 4 + qh * 2];
            ss += p[0]; sx += p[1];
        }
        const float sc = 0.08838834764831845f;  // 1/sqrt(128)
        ss *= sc; sx *= sc;
        float mm = fmaxf(ss, sx);
        float e0 = __expf(ss - mm), e1 = __expf(sx - mm);
        float inv = 1.f / (e0 + e1);
        attn[atom * 4 + qh * 2] = e0 * inv;
        attn[atom * 4 + qh * 2 + 1] = e1 * inv;
    }
    __syncthreads();  // B3: attn ready; sco2 dead -> lx region

    // V apply -> lx[row][head*128+h]
    #pragma unroll
    for (int m = 0; m < 2; m++) {
        #pragma unroll
        for (int v = 0; v < 4; v++) {
            int row = m * 16 + kq * 4 + v;
            f2v a = *(const f2v*)&attn[row * 4 + head * 2];
            float vv = acc[m][2][v];
            float vx = dpp_mov_f<0x128>(vv);   // cross-head V
            lx[row * 264 + head * 128 + h] = f2b(a[0] * vv + a[1] * vx);
        }
    }
    __syncthreads();  // B4: lx ready

    // ---- x @ W_o (K=256), B frags from L2; two independent MFMA chains ----
    const int mb = w >> 3, ch = w & 7;
    f4v oa, ob;
    #pragma unroll
    for (int v = 0; v < 4; v++) { oa[v] = 0.f; ob[v] = 0.f; }
    const u16* xp = lx + (mb * 16 + r16) * 264 + kq * 8;
    const u16* wp2 = wow + (ch * 16 + r16) * 32 + kq * 8;
    #pragma unroll
    for (int ks = 0; ks < 4; ks++) {
        s8v a0 = *(const s8v*)&xp[ks * 32];
        s8v b0 = *(const s8v*)&wp2[ks * 4096];
        s8v a1 = *(const s8v*)&xp[(ks + 4) * 32];
        s8v b1 = *(const s8v*)&wp2[(ks + 4) * 4096];
        oa = __builtin_amdgcn_mfma_f32_16x16x32_bf16(a0, b0, oa, 0, 0, 0);
        ob = __builtin_amdgcn_mfma_f32_16x16x32_bf16(a1, b1, ob, 0, 0, 0);
    }

    // ---- epilogue: LN2 partials (red16), cross-wave via pp ----
    const int col = ch * 16 + r16;
    const float boc = bo[col];
    float xo[4];
    #pragma unroll
    for (int v = 0; v < 4; v++) {
        xo[v] = oa[v] + ob[v] + boc;
        float s = red16(xo[v]);
        float s2 = red16(xo[v] * xo[v]);
        if (r16 == 0) {
            int row = mb * 16 + kq * 4 + v;
            f2v pr; pr[0] = s; pr[1] = s2;
            *(f2v*)&pp[(row * 8 + ch) * 2] = pr;
        }
    }
    __syncthreads();  // B5

    const float gac = g2[col], bbc = b2[col];
    #pragma unroll
    for (int v = 0; v < 4; v++) {
        int row = mb * 16 + kq * 4 + v;
        f4v p0 = *(f4v*)&pp[row * 16];
        f4v p1 = *(f4v*)&pp[row * 16 + 4];
        f4v p2 = *(f4v*)&pp[row * 16 + 8];
        f4v p3 = *(f4v*)&pp[row * 16 + 12];
        float ssum = p0[0] + p0[2] + p1[0] + p1[2] + p2[0] + p2[2] + p3[0] + p3[2];
        float s2sum = p0[1] + p0[3] + p1[1] + p1[3] + p2[1] + p2[3] + p3[1] + p3[3];
        float mu = ssum * (1.f / 128.f);
        float var = s2sum * (1.f / 128.f) - mu * mu;
        float rs = rsqrtf(var + 1e-5f);
        out[(abase + row) * 128 + col] =
            gac * (xo[v] - mu) * rs + bbc + b2f(lh0[row * 136 + col]);
    }
}

extern "C" void kernel_launch(void* const* d_in, const int* in_sizes, int n_in,
                              void* d_out, int out_size, void* d_ws, size_t ws_size,
                              hipStream_t stream) {
    const float* f_atoms = (const float*)d_in[0];
    const float* f_bonds = (const float*)d_in[1];
    const int* a2a = (const int*)d_in[2];
    const int* a2b = (const int*)d_in[3];
    const float* W_i = (const float*)d_in[4];
    const float* b_i = (const float*)d_in[5];
    const float* ln1g = (const float*)d_in[6];
    const float* ln1b = (const float*)d_in[7];
    const float* Whq = (const float*)d_in[8];
    const float* bhq = (const float*)d_in[9];
    const float* Whk = (const float*)d_in[10];
    const float* bhk = (const float*)d_in[11];
    const float* Whv = (const float*)d_in[12];
    const float* bhv = (const float*)d_in[13];
    const float* Wo = (const float*)d_in[14];
    const float* bo = (const float*)d_in[15];
    const float* ln2g = (const float*)d_in[16];
    const float* ln2b = (const float*)d_in[17];
    float* out = (float*)d_out;

    char* ws = (char*)d_ws;
    u16* h0w = (u16*)(ws + 0);                  //  51,200,000 B
    u16* fbw = (u16*)(ws + 51200000);           // 134,400,000 B
    u16* msga = (u16*)(ws + 185600000);         //  51,200,000 B
    u16* msgb = (u16*)(ws + 236800000);         //  67,200,000 B
    u16* wallw = (u16*)(ws + 304000000);        //     491,520 B
    u16* wow = (u16*)(ws + 304491520);          //      65,536 B
    u16* wiw = (u16*)(ws + 304557056);          //      40,960 B  (total ~304.6 MB)

    hipFuncSetAttribute(reinterpret_cast<const void*>(k_fused),
                        hipFuncAttributeMaxDynamicSharedMemorySize, SMEM_FUSED);

    k_prep<<<33981, 256, 0, stream>>>(Whq, Whk, Whv, Wo, W_i, wallw, wow, wiw,
                                      f_bonds, fbw);
    k_h0<<<3125, 256, H0_SMEM, stream>>>(f_atoms, wiw, b_i, ln1g, ln1b, h0w);
    k_msgab<<<28907, 256, 0, stream>>>(h0w, a2a, msga, fbw, a2b, msgb);
    k_fused<<<6250, 1024, SMEM_FUSED, stream>>>(h0w, msga, msgb, wallw, wow,
                                                bhq, bhk, bhv, bo, ln2g, ln2b, out);
}

// Round 12
// 519.740 us; speedup vs baseline: 1.0343x; 1.0343x over previous
//
#include <hip/hip_runtime.h>

typedef unsigned short u16;
typedef unsigned int u32;
typedef __attribute__((ext_vector_type(8))) short s8v;
typedef __attribute__((ext_vector_type(4))) float f4v;
typedef __attribute__((ext_vector_type(2))) float f2v;

#define NATOMS 200000
#define NBONDS 400000

// ---------- bf16 helpers ----------
__device__ __forceinline__ float b2f(u32 u) {
    union { u32 i; float f; } v; v.i = u << 16; return v.f;
}
__device__ __forceinline__ u16 f2b(float f) {
    union { float f; u32 i; } v; v.f = f;
    u32 r = v.i + 0x7fffu + ((v.i >> 16) & 1u);
    return (u16)(r >> 16);
}
__device__ __forceinline__ uint4 pack8(const float* f) {
    uint4 o;
    o.x = (u32)f2b(f[0]) | ((u32)f2b(f[1]) << 16);
    o.y = (u32)f2b(f[2]) | ((u32)f2b(f[3]) << 16);
    o.z = (u32)f2b(f[4]) | ((u32)f2b(f[5]) << 16);
    o.w = (u32)f2b(f[6]) | ((u32)f2b(f[7]) << 16);
    return o;
}
__device__ __forceinline__ void acc8(uint4 u, float* a) {
    a[0] += b2f(u.x & 0xffffu); a[1] += b2f(u.x >> 16);
    a[2] += b2f(u.y & 0xffffu); a[3] += b2f(u.y >> 16);
    a[4] += b2f(u.z & 0xffffu); a[5] += b2f(u.z >> 16);
    a[6] += b2f(u.w & 0xffffu); a[7] += b2f(u.w >> 16);
}

// ---------- cross-lane reduce (r7/r10-proven mix: DPP xor1/xor2 + DS xor4 + DPP ror8) ----------
template<int C>
__device__ __forceinline__ float dpp_mov_f(float x) {
    return __int_as_float(__builtin_amdgcn_update_dpp(
        0, __float_as_int(x), C, 0xF, 0xF, true));
}
__device__ __forceinline__ float swz_xor4(float x) {
    return __int_as_float(__builtin_amdgcn_ds_swizzle(__float_as_int(x), 0x101F));
}
__device__ __forceinline__ float red8(float x) {   // sum over lane bits 0..2
    x += dpp_mov_f<0xB1>(x);
    x += dpp_mov_f<0x4E>(x);
    x += swz_xor4(x);
    return x;
}
__device__ __forceinline__ float red16(float x) {  // sum over lane bits 0..3
    x += dpp_mov_f<0xB1>(x);
    x += dpp_mov_f<0x4E>(x);
    x += swz_xor4(x);
    x += dpp_mov_f<0x128>(x);
    return x;
}

// ---------- merged prep: weight repack + f_bonds bf16 table ----------
// blocks [0,1168): wallw [10 ks][768 n'][32 kk] (n' = (h>>3)*48 + branch*16 + head*8 + (h&7)),
//                  wow [8][128][32], wiw [5][128][32]
// blocks [1168,33981): fbw [NBONDS][168] (165 + 3 zero pad)
__global__ void k_prep(const float* __restrict__ Whq, const float* __restrict__ Whk,
                       const float* __restrict__ Whv, const float* __restrict__ Wo,
                       const float* __restrict__ Wi,
                       u16* __restrict__ wallw, u16* __restrict__ wow, u16* __restrict__ wiw,
                       const float* __restrict__ fb, u16* __restrict__ fbw) {
    if (blockIdx.x < 1168) {
        int t = blockIdx.x * 256 + threadIdx.x;
        if (t < 245760) {
            int ks = t / 24576, rem = t % 24576;
            int n = rem >> 5, kk = rem & 31;
            int k = ks * 32 + kk;
            int hg = n / 48, r48 = n % 48;
            int branch = r48 >> 4, r16i = r48 & 15;
            int head = r16i >> 3, h = hg * 8 + (r16i & 7);
            const float* Wp = (branch == 0) ? Whq : ((branch == 1) ? Whk : Whv);
            float val = (k < 293) ? Wp[(head * 293 + k) * 128 + h] : 0.f;
            wallw[t] = f2b(val);
        } else if (t < 278528) {
            int u = t - 245760;
            int ks = u >> 12, n = (u >> 5) & 127, kk = u & 31;
            int k = ks * 32 + kk;
            wow[u] = f2b(Wo[k * 128 + n]);
        } else if (t < 299008) {
            int u = t - 278528;
            int ks = u >> 12, n = (u >> 5) & 127, kk = u & 31;
            int k = ks * 32 + kk;
            wiw[u] = (k < 151) ? f2b(Wi[k * 128 + n]) : (u16)0;
        }
    } else {
        int t = (blockIdx.x - 1168) * 256 + threadIdx.x;
        if (t >= NBONDS * 21) return;
        u32 b = (u32)t / 21u, c = (u32)t % 21u;
        const float* src = fb + (size_t)b * 165 + c * 8;
        float a[8];
        #pragma unroll
        for (int q = 0; q < 8; q++) a[q] = ((int)(c * 8 + q) < 165) ? src[q] : 0.f;
        *(uint4*)&fbw[(size_t)b * 168 + c * 8] = pack8(a);
    }
}

// ---------- merged: h0 = LN(relu(f_atoms @ W_i + b_i)) -> bf16  [blocks 0..3125)
//            + per-atom bond-sum msgb[atom] = sum_j fbw[a2b[atom,j]]  [blocks 3125..19532)
// Both depend only on k_prep outputs -> run concurrently, mixing MFMA/VALU blocks
// with latency-bound gather blocks on the same CUs.
#define H0_SMEM 23552
__global__ __launch_bounds__(256) void k_h0msgb(
    const float* __restrict__ fa, const u16* __restrict__ wiw,
    const float* __restrict__ bi, const float* __restrict__ g1p, const float* __restrict__ b1p,
    u16* __restrict__ h0w,
    const u16* __restrict__ fbw, const int* __restrict__ a2b, u16* __restrict__ msgb) {
    if (blockIdx.x >= 3125) {
        // ---- msgb gather branch (no LDS use) ----
        int t = (blockIdx.x - 3125) * 256 + threadIdx.x;
        if (t >= NATOMS * 21) return;
        u32 atom = (u32)t / 21u, c = (u32)t % 21u;
        const int* nb = a2b + (size_t)atom * 6;
        float a[8] = {0, 0, 0, 0, 0, 0, 0, 0};
        #pragma unroll
        for (int j = 0; j < 6; j++)
            acc8(*(const uint4*)&fbw[(size_t)(u32)nb[j] * 168 + c * 8], a);
        *(uint4*)&msgb[(size_t)atom * 168 + c * 8] = pack8(a);
        return;
    }
    // ---- h0 branch ----
    extern __shared__ char smem[];
    u16* la = (u16*)smem;                 // [64][168]
    float* pp = (float*)(smem + 21504);   // [64][4][2]
    const int tid = threadIdx.x;
    const size_t abase = (size_t)blockIdx.x * 64;

    for (int i = tid; i < 64 * 151; i += 256) {
        int r = i / 151, c = i - r * 151;
        la[r * 168 + c] = f2b(fa[(abase + r) * 151 + c]);
    }
    for (int i = tid; i < 64 * 17; i += 256) {
        int r = i / 17, c = i - r * 17;
        la[r * 168 + 151 + c] = 0;
    }
    __syncthreads();

    const int w = tid >> 6, l = tid & 63;
    const int r16 = l & 15, kq = l >> 4;
    f4v acc[4][2];
    #pragma unroll
    for (int m = 0; m < 4; m++)
        #pragma unroll
        for (int c = 0; c < 2; c++)
            #pragma unroll
            for (int v = 0; v < 4; v++) acc[m][c][v] = 0.f;

    #pragma unroll
    for (int ks = 0; ks < 5; ++ks) {
        s8v af[4];
        #pragma unroll
        for (int m = 0; m < 4; m++)
            af[m] = *(const s8v*)&la[(m * 16 + r16) * 168 + ks * 32 + kq * 8];
        #pragma unroll
        for (int c = 0; c < 2; c++) {
            int n = w * 32 + c * 16 + r16;
            s8v bf = *(const s8v*)&wiw[ks * 4096 + n * 32 + kq * 8];
            #pragma unroll
            for (int m = 0; m < 4; m++)
                acc[m][c] = __builtin_amdgcn_mfma_f32_16x16x32_bf16(af[m], bf, acc[m][c], 0, 0, 0);
        }
    }

    const int col0 = w * 32 + r16, col1 = col0 + 16;
    const float bi0 = bi[col0], bi1 = bi[col1];
    #pragma unroll
    for (int m = 0; m < 4; m++) {
        #pragma unroll
        for (int v = 0; v < 4; v++) {
            acc[m][0][v] = fmaxf(acc[m][0][v] + bi0, 0.f);
            acc[m][1][v] = fmaxf(acc[m][1][v] + bi1, 0.f);
            float s = red16(acc[m][0][v] + acc[m][1][v]);
            float s2 = red16(acc[m][0][v] * acc[m][0][v] + acc[m][1][v] * acc[m][1][v]);
            if (r16 == 0) {
                int row = m * 16 + kq * 4 + v;
                f2v pr; pr[0] = s; pr[1] = s2;
                *(f2v*)&pp[(row * 4 + w) * 2] = pr;
            }
        }
    }
    __syncthreads();

    const float g0 = g1p[col0], g1v = g1p[col1];
    const float e0 = b1p[col0], e1 = b1p[col1];
    #pragma unroll
    for (int m = 0; m < 4; m++) {
        #pragma unroll
        for (int v = 0; v < 4; v++) {
            int row = m * 16 + kq * 4 + v;
            f4v p0 = *(f4v*)&pp[row * 8];
            f4v p1 = *(f4v*)&pp[row * 8 + 4];
            float ssum = p0[0] + p0[2] + p1[0] + p1[2];
            float s2sum = p0[1] + p0[3] + p1[1] + p1[3];
            float mu = ssum * (1.f / 128.f);
            float var = s2sum * (1.f / 128.f) - mu * mu;
            float rs = rsqrtf(var + 1e-5f);
            u16* orow = h0w + (abase + row) * 128;
            orow[col0] = f2b(g0 * (acc[m][0][v] - mu) * rs + e0);
            orow[col1] = f2b(g1v * (acc[m][1][v] - mu) * rs + e1);
        }
    }
}

// ---------- per-atom h0-sum: msga[atom] = sum_j h0[a2a[atom,j]] ([128] bf16) ----------
__global__ void k_msga(const u16* __restrict__ h0w, const int* __restrict__ a2a,
                       u16* __restrict__ msga) {
    int t = blockIdx.x * 256 + threadIdx.x;
    if (t >= NATOMS * 16) return;
    u32 atom = (u32)t >> 4, c = (u32)t & 15u;
    const int* na = a2a + (size_t)atom * 6;
    float a[8] = {0, 0, 0, 0, 0, 0, 0, 0};
    #pragma unroll
    for (int j = 0; j < 6; j++)
        acc8(*(const uint4*)&h0w[(size_t)(u32)na[j] * 128 + c * 8], a);
    *(uint4*)&msga[(size_t)atom * 128 + c * 8] = pack8(a);
}

// ---------- fused (r10-proven best): stage + QKV proj + attention + W_o + LN2 + residual ----
// 32 atoms/block, 1024 threads (16 waves), 2 blocks/CU (LDS 29184, VGPR<=64).
// LDS region0 @0 (20480): lmsg [32][320] bf16 XOR-swizzled (K-loop)
//   after B1.5 overlays: sco2 f32 [16][32][4] @0 (8192)
//   after B3   overlays: lx bf16 [32][264] @0 (16896)
//   attn f32 [32][4] @16896 (512) | pp f32 [32][8][2] @17408 (2048)
// lh0 [32][136] bf16 @20480 (8704, whole kernel)
#define SMEM_FUSED 29184
__global__ __launch_bounds__(1024, 8) void k_fused(
    const u16* __restrict__ h0w, const u16* __restrict__ msga, const u16* __restrict__ msgb,
    const u16* __restrict__ wallw, const u16* __restrict__ wow,
    const float* __restrict__ bhq, const float* __restrict__ bhk, const float* __restrict__ bhv,
    const float* __restrict__ bo, const float* __restrict__ g2, const float* __restrict__ b2,
    float* __restrict__ out) {
    extern __shared__ char smem[];
    float* sco2 = (float*)smem;             // overlays lmsg after B1.5
    u16* lx = (u16*)smem;                   // overlays sco2 after B3
    float* attn = (float*)(smem + 16896);
    float* pp = (float*)(smem + 17408);
    u16* lh0 = (u16*)(smem + 20480);        // stride 136 (bank-spread)

    const int tid = threadIdx.x;
    const size_t abase = (size_t)blockIdx.x * 32;
    const int w = tid >> 6, l = tid & 63;
    const int r16 = l & 15, kq = l >> 4;
    const u32 xmask = (u32)((r16 & 7) << 4);

    // B-frag prefetch for first K-step (L2-resident wallw)
    const u16* bp = wallw + (size_t)(w * 48 + r16) * 32 + kq * 8;
    s8v bfA0 = *(const s8v*)&bp[0];
    s8v bfA1 = *(const s8v*)&bp[512];
    s8v bfA2 = *(const s8v*)&bp[1024];

    // stage own h0 tile (coalesced), stride 136
    if (tid < 512) {
        int r = tid >> 4, c8 = tid & 15;
        *(uint4*)&lh0[r * 136 + c8 * 8] = *(const uint4*)&h0w[(abase + r) * 128 + c8 * 8];
    }

    // stage msg tile into swizzled LDS — fully coalesced reads:
    // item c: 0..15 -> msga cols c*8 | 16..36 -> msgb cols (c-16)*8 | 37..39 -> zeros
    #pragma unroll
    for (int ii = 0; ii < 2; ++ii) {
        int i = tid + ii * 1024;
        if (i < 1280) {
            int r = i / 40, c = i - r * 40;
            uint4 val;
            if (c < 16) {
                val = *(const uint4*)&msga[(abase + r) * 128 + c * 8];
            } else if (c < 37) {
                val = *(const uint4*)&msgb[(abase + r) * 168 + (c - 16) * 8];
            } else {
                val = (uint4){0, 0, 0, 0};
            }
            *(uint4*)(smem + (((u32)(r * 640 + c * 16)) ^ ((u32)((r & 7) << 4)))) = val;
        }
    }
    __syncthreads();  // B1: lmsg + lh0 ready

    f4v acc[2][3];
    #pragma unroll
    for (int m = 0; m < 2; m++)
        #pragma unroll
        for (int c = 0; c < 3; c++)
            #pragma unroll
            for (int v = 0; v < 4; v++) acc[m][c][v] = 0.f;

    s8v bfB0, bfB1, bfB2;
    // K-loop: 10 steps, A from swizzled LDS, B double-buffered from L2, no barriers.
    #pragma unroll
    for (int kp = 0; kp < 5; ++kp) {
        {   // even step uses bfA, prefetch bfB
            const int ks = 2 * kp;
            const u16* nb = bp + (size_t)(ks + 1) * 24576;
            bfB0 = *(const s8v*)&nb[0];
            bfB1 = *(const s8v*)&nb[512];
            bfB2 = *(const s8v*)&nb[1024];
            #pragma unroll
            for (int m = 0; m < 2; m++) {
                s8v af = *(const s8v*)(smem +
                    (((u32)((m * 16 + r16) * 640 + ks * 64 + kq * 16)) ^ xmask));
                acc[m][0] = __builtin_amdgcn_mfma_f32_16x16x32_bf16(af, bfA0, acc[m][0], 0, 0, 0);
                acc[m][1] = __builtin_amdgcn_mfma_f32_16x16x32_bf16(af, bfA1, acc[m][1], 0, 0, 0);
                acc[m][2] = __builtin_amdgcn_mfma_f32_16x16x32_bf16(af, bfA2, acc[m][2], 0, 0, 0);
            }
        }
        {   // odd step uses bfB, prefetch bfA
            const int ks = 2 * kp + 1;
            if (kp < 4) {
                const u16* nb = bp + (size_t)(ks + 1) * 24576;
                bfA0 = *(const s8v*)&nb[0];
                bfA1 = *(const s8v*)&nb[512];
                bfA2 = *(const s8v*)&nb[1024];
            }
            #pragma unroll
            for (int m = 0; m < 2; m++) {
                s8v af = *(const s8v*)(smem +
                    (((u32)((m * 16 + r16) * 640 + ks * 64 + kq * 16)) ^ xmask));
                acc[m][0] = __builtin_amdgcn_mfma_f32_16x16x32_bf16(af, bfB0, acc[m][0], 0, 0, 0);
                acc[m][1] = __builtin_amdgcn_mfma_f32_16x16x32_bf16(af, bfB1, acc[m][1], 0, 0, 0);
                acc[m][2] = __builtin_amdgcn_mfma_f32_16x16x32_bf16(af, bfB2, acc[m][2], 0, 0, 0);
            }
        }
    }
    __syncthreads();  // B1.5: lmsg reads done -> region0 reusable as sco2

    // QKV relu + per-head score partials (h0 from lh0).
    const int head = r16 >> 3;
    const int h = w * 8 + (r16 & 7);
    const float bq = bhq[head * 128 + h];
    const float bk = bhk[head * 128 + h];
    const float bv = bhv[head * 128 + h];
    #pragma unroll
    for (int m = 0; m < 2; m++) {
        #pragma unroll
        for (int v = 0; v < 4; v++) {
            int row = m * 16 + kq * 4 + v;
            float h0v = b2f(lh0[row * 136 + h]);
            float q  = fmaxf(acc[m][0][v] + h0v + bq, 0.f);
            float kk = fmaxf(acc[m][1][v] + h0v + bk, 0.f);
            float vv = fmaxf(acc[m][2][v] + h0v + bv, 0.f);
            acc[m][2][v] = vv;  // keep relu'd V
            float kx = dpp_mov_f<0x128>(kk);   // cross-head K (xor8 within 16)
            float pA = red8(q * kk);           // q_head . k_head
            float pB = red8(q * kx);           // q_head . k_other
            if ((r16 & 7) == (m * 4 + v)) {
                f2v pr; pr[0] = pA; pr[1] = pB;
                *(f2v*)&sco2[(w * 32 + row) * 4 + head * 2] = pr;
            }
        }
    }
    __syncthreads();  // B2: sco2 ready

    // softmax over heads: 64 threads, one per (atom, query-head)
    if (tid < 64) {
        int atom = tid >> 1, qh = tid & 1;
        float ss = 0.f, sx = 0.f;
        #pragma unroll
        for (int ww = 0; ww < 16; ww++) {
            f2v p = *(const f2v*)&sco2[(ww * 32 + atom) * 4 + qh * 2];
            ss += p[0]; sx += p[1];
        }
        const float sc = 0.08838834764831845f;  // 1/sqrt(128)
        ss *= sc; sx *= sc;
        float mm = fmaxf(ss, sx);
        float e0 = __expf(ss - mm), e1 = __expf(sx - mm);
        float inv = 1.f / (e0 + e1);
        attn[atom * 4 + qh * 2] = e0 * inv;
        attn[atom * 4 + qh * 2 + 1] = e1 * inv;
    }
    __syncthreads();  // B3: attn ready; sco2 dead -> lx region

    // V apply -> lx[row][head*128+h]
    #pragma unroll
    for (int m = 0; m < 2; m++) {
        #pragma unroll
        for (int v = 0; v < 4; v++) {
            int row = m * 16 + kq * 4 + v;
            f2v a = *(const f2v*)&attn[row * 4 + head * 2];
            float vv = acc[m][2][v];
            float vx = dpp_mov_f<0x128>(vv);   // cross-head V
            lx[row * 264 + head * 128 + h] = f2b(a[0] * vv + a[1] * vx);
        }
    }
    __syncthreads();  // B4: lx ready

    // ---- x @ W_o (K=256), B frags straight from L2 ----
    const int mb = w >> 3, ch = w & 7;
    f4v oa;
    #pragma unroll
    for (int v = 0; v < 4; v++) oa[v] = 0.f;
    const u16* xp = lx + (mb * 16 + r16) * 264 + kq * 8;
    const u16* wp2 = wow + (ch * 16 + r16) * 32 + kq * 8;
    #pragma unroll
    for (int ks = 0; ks < 8; ks++) {
        s8v a = *(const s8v*)&xp[ks * 32];
        s8v b = *(const s8v*)&wp2[ks * 4096];
        oa = __builtin_amdgcn_mfma_f32_16x16x32_bf16(a, b, oa, 0, 0, 0);
    }

    // ---- epilogue: LN2 partials (red16), cross-wave via pp ----
    const int col = ch * 16 + r16;
    const float boc = bo[col];
    float xo[4];
    #pragma unroll
    for (int v = 0; v < 4; v++) {
        xo[v] = oa[v] + boc;
        float s = red16(xo[v]);
        float s2 = red16(xo[v] * xo[v]);
        if (r16 == 0) {
            int row = mb * 16 + kq * 4 + v;
            f2v pr; pr[0] = s; pr[1] = s2;
            *(f2v*)&pp[(row * 8 + ch) * 2] = pr;
        }
    }
    __syncthreads();  // B5

    const float gac = g2[col], bbc = b2[col];
    #pragma unroll
    for (int v = 0; v < 4; v++) {
        int row = mb * 16 + kq * 4 + v;
        f4v p0 = *(f4v*)&pp[row * 16];
        f4v p1 = *(f4v*)&pp[row * 16 + 4];
        f4v p2 = *(f4v*)&pp[row * 16 + 8];
        f4v p3 = *(f4v*)&pp[row * 16 + 12];
        float ssum = p0[0] + p0[2] + p1[0] + p1[2] + p2[0] + p2[2] + p3[0] + p3[2];
        float s2sum = p0[1] + p0[3] + p1[1] + p1[3] + p2[1] + p2[3] + p3[1] + p3[3];
        float mu = ssum * (1.f / 128.f);
        float var = s2sum * (1.f / 128.f) - mu * mu;
        float rs = rsqrtf(var + 1e-5f);
        out[(abase + row) * 128 + col] =
            gac * (xo[v] - mu) * rs + bbc + b2f(lh0[row * 136 + col]);
    }
}

extern "C" void kernel_launch(void* const* d_in, const int* in_sizes, int n_in,
                              void* d_out, int out_size, void* d_ws, size_t ws_size,
                              hipStream_t stream) {
    const float* f_atoms = (const float*)d_in[0];
    const float* f_bonds = (const float*)d_in[1];
    const int* a2a = (const int*)d_in[2];
    const int* a2b = (const int*)d_in[3];
    const float* W_i = (const float*)d_in[4];
    const float* b_i = (const float*)d_in[5];
    const float* ln1g = (const float*)d_in[6];
    const float* ln1b = (const float*)d_in[7];
    const float* Whq = (const float*)d_in[8];
    const float* bhq = (const float*)d_in[9];
    const float* Whk = (const float*)d_in[10];
    const float* bhk = (const float*)d_in[11];
    const float* Whv = (const float*)d_in[12];
    const float* bhv = (const float*)d_in[13];
    const float* Wo = (const float*)d_in[14];
    const float* bo = (const float*)d_in[15];
    const float* ln2g = (const float*)d_in[16];
    const float* ln2b = (const float*)d_in[17];
    float* out = (float*)d_out;

    char* ws = (char*)d_ws;
    u16* h0w = (u16*)(ws + 0);                  //  51,200,000 B
    u16* fbw = (u16*)(ws + 51200000);           // 134,400,000 B
    u16* msga = (u16*)(ws + 185600000);         //  51,200,000 B
    u16* msgb = (u16*)(ws + 236800000);         //  67,200,000 B
    u16* wallw = (u16*)(ws + 304000000);        //     491,520 B
    u16* wow = (u16*)(ws + 304491520);          //      65,536 B
    u16* wiw = (u16*)(ws + 304557056);          //      40,960 B  (total ~304.6 MB)

    hipFuncSetAttribute(reinterpret_cast<const void*>(k_fused),
                        hipFuncAttributeMaxDynamicSharedMemorySize, SMEM_FUSED);

    k_prep<<<33981, 256, 0, stream>>>(Whq, Whk, Whv, Wo, W_i, wallw, wow, wiw,
                                      f_bonds, fbw);
    // h0 (blocks 0..3125) runs concurrently with the bond gather (blocks 3125..19532):
    // independent inputs (wiw/f_atoms vs fbw/a2b), mixing compute- and latency-bound blocks.
    k_h0msgb<<<19532, 256, H0_SMEM, stream>>>(f_atoms, wiw, b_i, ln1g, ln1b, h0w,
                                              fbw, a2b, msgb);
    k_msga<<<12500, 256, 0, stream>>>(h0w, a2a, msga);
    k_fused<<<6250, 1024, SMEM_FUSED, stream>>>(h0w, msga, msgb, wallw, wow,
                                                bhq, bhk, bhv, bo, ln2g, ln2b, out);
}